// Round 4
// baseline (407.038 us; speedup 1.0000x reference)
//
#include <hip/hip_runtime.h>
#include <hip/hip_bf16.h>

// B=4, C=64, D=32, H=64, W=64, S=32. fp32 I/O, bf16 MFMA compute.
#define Bn 4
#define Cn 64
#define Dn 32
#define Sn 32
#define Hn 64
#define Wn 64
#define HWn 4096
#define NT 256

// Per-wave LDS slice (shorts). Aliased in time:
//   phase1: xT[64 rows][66]  (rows n_local = (site&1)*32 + d, cols c)
//   phase2: kT[2][32][34] (+0) and vb[2][32][36] (+2176)
//   phase3: outT[64][66]
#define SLICE   4608      // shorts = 9216 B per wave
#define XPITCH  66
#define KT_SITE 1088      // 32*34
#define VB_OFF  2176
#define VB_SITE 1152      // 32*36
#define BIAS_U32 9216     // uint index where bias floats start (160 floats)

typedef float f16v __attribute__((ext_vector_type(16)));
typedef short s8v  __attribute__((ext_vector_type(8)));
#define MFMA(a,b,c) __builtin_amdgcn_mfma_f32_32x32x16_bf16((a),(b),(c),0,0,0)

union frag_u { s8v v; unsigned short u[8]; unsigned int d[4]; };

__device__ __forceinline__ unsigned short f2bf(float f){
    union { __hip_bfloat16 h; unsigned short u; } cv; cv.h = __float2bfloat16(f); return cv.u;
}
__device__ __forceinline__ float bf2f(unsigned short u){
    return __uint_as_float(((unsigned int)u)<<16);
}
__device__ __forceinline__ f16v zero16(){
    f16v z;
#pragma unroll
    for(int i=0;i<16;++i) z[i]=0.f;
    return z;
}
// A-operand fragment from a row-major fp32 weight matrix: A[m=row][k=c0..c0+7]
__device__ __forceinline__ s8v wfrag(const float* __restrict__ W, int stride, int row, int c0){
    const float4 a = *(const float4*)(W + row*stride + c0);
    const float4 b = *(const float4*)(W + row*stride + c0 + 4);
    frag_u f;
    f.u[0]=f2bf(a.x); f.u[1]=f2bf(a.y); f.u[2]=f2bf(a.z); f.u[3]=f2bf(a.w);
    f.u[4]=f2bf(b.x); f.u[5]=f2bf(b.y); f.u[6]=f2bf(b.z); f.u[7]=f2bf(b.w);
    return f.v;
}
// Assemble B-operand fragment (chunk ch of a K=32 contraction) from C/D-layout
// fp32 regs a[16] + their shfl_xor(32) partners sw[16].
// C/D row of reg r = (r&3)+8*(r>>2)+4*hi; B needs k = ch*16 + hi*8 + e.
__device__ __forceinline__ s8v bfrag(const float a[16], const float sw[16], int ch, int hi){
    frag_u f;
    const int b = ch*8;
#pragma unroll
    for(int j=0;j<4;++j){
        const float lo = hi ? sw[b+4+j] : a[b+j];    // e = j
        const float hh = hi ? a[b+4+j]  : sw[b+j];   // e = 4+j
        f.u[j]   = f2bf(lo);
        f.u[4+j] = f2bf(hh);
    }
    return f.v;
}

__global__ __launch_bounds__(NT, 4) void attn_kernel(
    const float* __restrict__ x,
    const float* __restrict__ Wk, const float* __restrict__ bk,
    const float* __restrict__ Wq, const float* __restrict__ bq,
    const float* __restrict__ Wv, const float* __restrict__ bv,
    const float* __restrict__ Wo, const float* __restrict__ bo,
    float* __restrict__ out)
{
    __shared__ unsigned int lds32[BIAS_U32 + 160];   // 4 slices + biases = 37.5 KB
    unsigned short* lds16 = (unsigned short*)lds32;
    float* biasf = (float*)(lds32 + BIAS_U32);

    const int t = threadIdx.x;
    // XCD pair swizzle: blocks i,i+8 share 64B x/out lines via L2
    const int ib = blockIdx.x;
    const int member = (ib>>3)&1;
    const int pp = (ib&7) | ((ib>>4)<<3);
    const int wpair = pp & 3;
    const int bh = pp >> 2;
    const int h = bh & (Hn-1);
    const int b = bh >> 6;
    const int w0 = wpair*16 + member*8;
    const size_t base = (size_t)b*(Cn*Dn*HWn) + h*Wn + w0;

    // ---- Phase 0: stage x -> xT bf16 (transposed [n][c], per-wave slices).
    //      Keep the bf16-packed residual words in registers (no re-read). ----
    unsigned int res[4][8];
#pragma unroll
    for (int it=0; it<4; ++it){
        const int u = t + it*NT;
        const int cp = u>>5, d = u&31;
        const float* p0 = x + base + (size_t)((2*cp)*Dn + d)*HWn;
        const float* p1 = p0 + (size_t)Dn*HWn;
        const float4 a0 = ((const float4*)p0)[0], a1 = ((const float4*)p0)[1];
        const float4 b0 = ((const float4*)p1)[0], b1 = ((const float4*)p1)[1];
        const float r0[8] = {a0.x,a0.y,a0.z,a0.w,a1.x,a1.y,a1.z,a1.w};
        const float r1[8] = {b0.x,b0.y,b0.z,b0.w,b1.x,b1.y,b1.z,b1.w};
#pragma unroll
        for(int site=0;site<8;++site){
            const unsigned int pk = (unsigned int)f2bf(r0[site])
                                  | ((unsigned int)f2bf(r1[site])<<16);
            res[it][site] = pk;
            const int off = (site>>1)*SLICE + (((site&1)<<5)+d)*XPITCH + 2*cp;
            lds32[off>>1] = pk;   // shorts (2cp,2cp+1) of row n=site*32+d
        }
    }
    if (t < 160){
        const float v = (t<32)? bk[t] : (t<64)? bq[t-32] : (t<96)? bv[t-64] : bo[t-96];
        biasf[t] = v;
    }
    __syncthreads();

    const int wv = t>>6, lane = t&63, ln = lane&31, hi = lane>>5;
    const int WSH = wv*SLICE;

    // ---- B-fragments of X for this wave's 2 sites (frees xT slice afterwards) ----
    frag_u xb[2][4];
#pragma unroll
    for(int st=0;st<2;++st){
        const int nl = (st<<5)+ln;
#pragma unroll
        for(int kc=0;kc<4;++kc){
            const unsigned int* q = lds32 + ((WSH + nl*XPITCH + kc*16 + hi*8)>>1);
            xb[st][kc].d[0]=q[0]; xb[st][kc].d[1]=q[1];
            xb[st][kc].d[2]=q[2]; xb[st][kc].d[3]=q[3];
        }
    }
    const float scale = 0.17677669529663687f;   // 1/sqrt(32)

    // ---- K = Wk @ X  -> kT[site][i][s] (bias+scale folded), aliases xT slice ----
    {
        f16v k0=zero16(), k1=zero16();
#pragma unroll
        for(int kc=0;kc<4;++kc){
            const s8v wa = wfrag(Wk, Cn, ln, kc*16+hi*8);
            k0 = MFMA(wa, xb[0][kc].v, k0);
            k1 = MFMA(wa, xb[1][kc].v, k1);
        }
#pragma unroll
        for(int r=0;r<16;++r){
            const int s = (r&3)+8*(r>>2)+4*hi;
            lds16[WSH + 0*KT_SITE + ln*34 + s] = f2bf((k0[r]+biasf[s])*scale);
            lds16[WSH + 1*KT_SITE + ln*34 + s] = f2bf((k1[r]+biasf[s])*scale);
        }
    }
    // ---- Q = Wq @ X  -> kept in registers as B-fragments ----
    frag_u qf[2][2];
    {
        f16v q0=zero16(), q1=zero16();
#pragma unroll
        for(int kc=0;kc<4;++kc){
            const s8v wa = wfrag(Wq, Cn, ln, kc*16+hi*8);
            q0 = MFMA(wa, xb[0][kc].v, q0);
            q1 = MFMA(wa, xb[1][kc].v, q1);
        }
        float qa[16], qb_[16], sw[16];
#pragma unroll
        for(int r=0;r<16;++r){
            const int s = (r&3)+8*(r>>2)+4*hi;
            qa[r]  = q0[r] + biasf[32+s];
            qb_[r] = q1[r] + biasf[32+s];
        }
#pragma unroll
        for(int r=0;r<16;++r) sw[r] = __shfl_xor(qa[r], 32);
        qf[0][0].v = bfrag(qa, sw, 0, hi);
        qf[0][1].v = bfrag(qa, sw, 1, hi);
#pragma unroll
        for(int r=0;r<16;++r) sw[r] = __shfl_xor(qb_[r], 32);
        qf[1][0].v = bfrag(qb_, sw, 0, hi);
        qf[1][1].v = bfrag(qb_, sw, 1, hi);
    }
    // ---- V = Wv @ X  -> vb[site][s][i] ----
    {
        f16v v0=zero16(), v1=zero16();
#pragma unroll
        for(int kc=0;kc<4;++kc){
            const s8v wa = wfrag(Wv, Cn, ln, kc*16+hi*8);
            v0 = MFMA(wa, xb[0][kc].v, v0);
            v1 = MFMA(wa, xb[1][kc].v, v1);
        }
#pragma unroll
        for(int r=0;r<16;++r){
            const int s = (r&3)+8*(r>>2)+4*hi;
            lds16[WSH + VB_OFF + 0*VB_SITE + s*36 + ln] = f2bf(v0[r]+biasf[64+s]);
            lds16[WSH + VB_OFF + 1*VB_SITE + s*36 + ln] = f2bf(v1[r]+biasf[64+s]);
        }
    }

    // ---- scores -> softmax(axis i) -> PV, per site; O kept as B-fragments ----
    frag_u of[2][2];
#pragma unroll
    for(int st=0; st<2; ++st){
        frag_u ka[2], va[2];
#pragma unroll
        for(int ch=0; ch<2; ++ch){
            const unsigned int* qk = lds32 + ((WSH + st*KT_SITE + ln*34 + ch*16 + hi*8)>>1);
            ka[ch].d[0]=qk[0]; ka[ch].d[1]=qk[1]; ka[ch].d[2]=qk[2]; ka[ch].d[3]=qk[3];
            const unsigned int* qv = lds32 + ((WSH + VB_OFF + st*VB_SITE + ln*36 + ch*16 + hi*8)>>1);
            va[ch].d[0]=qv[0]; va[ch].d[1]=qv[1]; va[ch].d[2]=qv[2]; va[ch].d[3]=qv[3];
        }
        f16v sc = zero16();                     // sc[i][j] = sum_s kT[i][s] q[s][j]
        sc = MFMA(ka[0].v, qf[st][0].v, sc);
        sc = MFMA(ka[1].v, qf[st][1].v, sc);

        float mx = sc[0];
#pragma unroll
        for(int r=1;r<16;++r) mx = fmaxf(mx, sc[r]);
        mx = fmaxf(mx, __shfl_xor(mx, 32));
        float pr[16]; float sm = 0.f;
#pragma unroll
        for(int r=0;r<16;++r){ pr[r] = __expf(sc[r]-mx); sm += pr[r]; }
        sm += __shfl_xor(sm, 32);
        const float inv = 1.f/sm;
#pragma unroll
        for(int r=0;r<16;++r) pr[r] *= inv;

        float swp[16];
#pragma unroll
        for(int r=0;r<16;++r) swp[r] = __shfl_xor(pr[r], 32);
        frag_u pf0, pf1;
        pf0.v = bfrag(pr, swp, 0, hi);
        pf1.v = bfrag(pr, swp, 1, hi);

        f16v ov = zero16();                     // o[s][j] = sum_i v[s][i] p[i][j]
        ov = MFMA(va[0].v, pf0.v, ov);
        ov = MFMA(va[1].v, pf1.v, ov);

        float oa_[16], swo[16];
#pragma unroll
        for(int r=0;r<16;++r) oa_[r] = ov[r];
#pragma unroll
        for(int r=0;r<16;++r) swo[r] = __shfl_xor(oa_[r], 32);
        of[st][0].v = bfrag(oa_, swo, 0, hi);
        of[st][1].v = bfrag(oa_, swo, 1, hi);
    }

    // ---- out-projection: D[c][n] = sum_s Wo[c][s] o[s][n] -> outT (aliases kT/vb) ----
    frag_u wo_[2][2];
#pragma unroll
    for(int mt=0; mt<2; ++mt)
#pragma unroll
        for(int ch=0; ch<2; ++ch)
            wo_[mt][ch].v = wfrag(Wo, Sn, mt*32+ln, ch*16+hi*8);
#pragma unroll
    for(int st=0; st<2; ++st){
#pragma unroll
        for(int mt=0; mt<2; ++mt){
            f16v oacc = zero16();
            oacc = MFMA(wo_[mt][0].v, of[st][0].v, oacc);
            oacc = MFMA(wo_[mt][1].v, of[st][1].v, oacc);
#pragma unroll
            for(int r=0;r<16;++r){
                const int c = mt*32 + (r&3)+8*(r>>2)+4*hi;
                lds16[WSH + ((st<<5)+ln)*XPITCH + c] = f2bf(oacc[r]);
            }
        }
    }
    __syncthreads();

    // ---- Epilogue: residual from registers + bo + coalesced fp32 store ----
#pragma unroll
    for (int it=0; it<4; ++it){
        const int u = t + it*NT;
        const int cp = u>>5, d = u&31;
        const int c0 = 2*cp, c1 = c0+1;
        const float bo0 = biasf[96+c0], bo1 = biasf[96+c1];
        float o0[8], o1[8];
#pragma unroll
        for(int site=0;site<8;++site){
            const int off = (site>>1)*SLICE + (((site&1)<<5)+d)*XPITCH + c0;
            const unsigned int pko = lds32[off>>1];
            const unsigned int pkr = res[it][site];
            o0[site] = bf2f((unsigned short)(pkr & 0xffffu)) + bo0
                     + bf2f((unsigned short)(pko & 0xffffu));
            o1[site] = bf2f((unsigned short)(pkr >> 16)) + bo1
                     + bf2f((unsigned short)(pko >> 16));
        }
        float* q0p = out + base + (size_t)(c0*Dn + d)*HWn;
        float* q1p = q0p + (size_t)Dn*HWn;
        ((float4*)q0p)[0] = make_float4(o0[0],o0[1],o0[2],o0[3]);
        ((float4*)q0p)[1] = make_float4(o0[4],o0[5],o0[6],o0[7]);
        ((float4*)q1p)[0] = make_float4(o1[0],o1[1],o1[2],o1[3]);
        ((float4*)q1p)[1] = make_float4(o1[4],o1[5],o1[6],o1[7]);
    }
}

extern "C" void kernel_launch(void* const* d_in, const int* in_sizes, int n_in,
                              void* d_out, int out_size, void* d_ws, size_t ws_size,
                              hipStream_t stream) {
    (void)in_sizes; (void)n_in; (void)d_ws; (void)ws_size; (void)out_size;
    const float* x  = (const float*)d_in[0];
    const float* Wk = (const float*)d_in[1];
    const float* bk = (const float*)d_in[2];
    const float* Wq = (const float*)d_in[3];
    const float* bq = (const float*)d_in[4];
    const float* Wv = (const float*)d_in[5];
    const float* bv = (const float*)d_in[6];
    const float* Wo = (const float*)d_in[7];
    const float* bo = (const float*)d_in[8];
    float* out = (float*)d_out;

    const int nblocks = Bn * Hn * (Wn / 8);   // 2048
    attn_kernel<<<dim3(nblocks), dim3(NT), 0, stream>>>(
        x, Wk, bk, Wq, bq, Wv, bv, Wo, bo, out);
}